// Round 5
// baseline (1092.486 us; speedup 1.0000x reference)
//
#include <hip/hip_runtime.h>
#include <hip/hip_fp16.h>
#include <cstdint>
#include <cstddef>

// ---------------------------------------------------------------------------
// GIN (GINEConv x3) forward, f32.
//   h  = x@W_enc + b_enc                                  (gemm_enc)
//   CSR build: hist -> scan -> scatter -> permute(srcp,attp) -> eabuild(f16)
//   per layer i:
//     agg:  z[v] = (1+eps_i) h[v] + sum_{e: dst=v} relu(h[src_e]+ea_e)*att_e
//           one wave per node, ea precomputed f16, 8-edge unrolled gather
//     mlp:  h = relu( relu(BN(z@W1+b1)) @ W2 + b2 )       (gemm_mlp fused)
// ---------------------------------------------------------------------------

// ---- packed-f32x2 atomic with compile-safe fallback (fallback path only) ---
template <class T>
__device__ inline auto add2_impl(T* p, T v, int)
    -> decltype(unsafeAtomicAdd(p, v), void()) {
    unsafeAtomicAdd(p, v);
}
template <class T>
__device__ inline void add2_impl(T* p, T v, long) {
    unsafeAtomicAdd(&p->x, v.x);
    unsafeAtomicAdd(&p->y, v.y);
}
__device__ inline void atomic_add2(float* p, float x, float y) {
    add2_impl(reinterpret_cast<float2*>(p), make_float2(x, y), 0);
}

// ---------------------------------------------------------------------------
// CSR build
// ---------------------------------------------------------------------------
__global__ void zero_cnt(int* __restrict__ cnt, int N)
{
    int i = blockIdx.x * blockDim.x + threadIdx.x;
    if (i < N) cnt[i] = 0;
}

__global__ void hist_kernel(const int* __restrict__ ei, int* __restrict__ cnt, int E)
{
    int i = blockIdx.x * blockDim.x + threadIdx.x;
    const int st = gridDim.x * blockDim.x;
    for (; i < E; i += st) atomicAdd(&cnt[ei[E + i]], 1);
}

// single-block exclusive scan of cnt[0..N) -> off, cur ; off[N]=E
__global__ __launch_bounds__(1024) void scan_kernel(
    const int* __restrict__ cnt, int* __restrict__ off, int* __restrict__ cur,
    int N, int E)
{
    __shared__ int part[1024];
    const int t = threadIdx.x;
    const int chunk = (N + 1023) / 1024;
    const int s0 = min(t * chunk, N), s1 = min(s0 + chunk, N);
    int sum = 0;
    for (int i = s0; i < s1; ++i) sum += cnt[i];
    part[t] = sum;
    __syncthreads();
    for (int d = 1; d < 1024; d <<= 1) {
        int v = (t >= d) ? part[t - d] : 0;
        __syncthreads();
        part[t] += v;
        __syncthreads();
    }
    int base = (t == 0) ? 0 : part[t - 1];
    for (int i = s0; i < s1; ++i) {
        off[i] = base; cur[i] = base;
        base += cnt[i];
    }
    if (t == 0) off[N] = E;
}

__global__ void scatter_kernel(const int* __restrict__ ei, int* __restrict__ cur,
                               int* __restrict__ eids, int E)
{
    int i = blockIdx.x * blockDim.x + threadIdx.x;
    const int st = gridDim.x * blockDim.x;
    for (; i < E; i += st) {
        int pos = atomicAdd(&cur[ei[E + i]], 1);
        eids[pos] = i;
    }
}

// permute src/att into CSR slot order
__global__ void permute_kernel(
    const int* __restrict__ ei, const float* __restrict__ eatten,
    const int* __restrict__ eids,
    int* __restrict__ srcp, float* __restrict__ attp, int E)
{
    int i = blockIdx.x * blockDim.x + threadIdx.x;
    const int st = gridDim.x * blockDim.x;
    for (; i < E; i += st) {
        const int eid = eids[i];
        srcp[i] = ei[eid];
        attp[i] = eatten[eid];
    }
}

// precompute ea = edge_attr@W_ee + b_ee in CSR slot order, packed half2.
// one wave per slot (grid-stride, 2-deep unroll); lane owns 2 cols.
__global__ __launch_bounds__(256) void eabuild_kernel(
    const int* __restrict__ eids, const float* __restrict__ eattr,
    const float* __restrict__ W_ee, const float* __restrict__ b_ee,
    uint32_t* __restrict__ eab, int E)
{
    const int t = threadIdx.x;
    const int lane = t & 63;
    const int c = lane * 2;
    float2 w[16];
#pragma unroll
    for (int k = 0; k < 16; ++k) w[k] = *(const float2*)&W_ee[k * 128 + c];
    const float2 bv = *(const float2*)&b_ee[c];

    const int wid = blockIdx.x * 4 + (t >> 6);
    const int nw = gridDim.x * 4;
    int slot = wid;
    for (; slot + nw < E; slot += 2 * nw) {
        const int s2 = slot + nw;
        const int eid0 = eids[slot], eid1 = eids[s2];
        float4 ev0[4], ev1[4];
        const float4* p0 = (const float4*)(eattr + (size_t)eid0 * 16);
        const float4* p1 = (const float4*)(eattr + (size_t)eid1 * 16);
#pragma unroll
        for (int q = 0; q < 4; ++q) { ev0[q] = p0[q]; ev1[q] = p1[q]; }
        const float* e0 = (const float*)&ev0[0];
        const float* e1 = (const float*)&ev1[0];
        float d00 = bv.x, d01 = bv.y, d10 = bv.x, d11 = bv.y;
#pragma unroll
        for (int k = 0; k < 16; ++k) {
            d00 = fmaf(e0[k], w[k].x, d00);
            d01 = fmaf(e0[k], w[k].y, d01);
            d10 = fmaf(e1[k], w[k].x, d10);
            d11 = fmaf(e1[k], w[k].y, d11);
        }
        __half2 h0 = __floats2half2_rn(d00, d01);
        __half2 h1 = __floats2half2_rn(d10, d11);
        eab[(size_t)slot * 64 + lane] = *reinterpret_cast<uint32_t*>(&h0);
        eab[(size_t)s2 * 64 + lane]   = *reinterpret_cast<uint32_t*>(&h1);
    }
    if (slot < E) {
        const int eid0 = eids[slot];
        float4 ev0[4];
        const float4* p0 = (const float4*)(eattr + (size_t)eid0 * 16);
#pragma unroll
        for (int q = 0; q < 4; ++q) ev0[q] = p0[q];
        const float* e0 = (const float*)&ev0[0];
        float d00 = bv.x, d01 = bv.y;
#pragma unroll
        for (int k = 0; k < 16; ++k) {
            d00 = fmaf(e0[k], w[k].x, d00);
            d01 = fmaf(e0[k], w[k].y, d01);
        }
        __half2 h0 = __floats2half2_rn(d00, d01);
        eab[(size_t)slot * 64 + lane] = *reinterpret_cast<uint32_t*>(&h0);
    }
}

// ---------------------------------------------------------------------------
// Aggregation (f16-ea tier): one wave per node, lane owns 2 cols.
// ---------------------------------------------------------------------------
__global__ __launch_bounds__(256) void agg_f16(
    const float* __restrict__ h, const int* __restrict__ srcp,
    const float* __restrict__ attp, const uint32_t* __restrict__ eab,
    const int* __restrict__ off,
    float* __restrict__ Z, const float* __restrict__ eps, int layer, int N)
{
    const int t = threadIdx.x;
    const int v = blockIdx.x * 4 + (t >> 6);
    if (v >= N) return;
    const int lane = t & 63;
    const int c = lane * 2;

    const int e0 = off[v], e1 = off[v + 1];
    float a0 = 0.f, a1 = 0.f;
    int e = e0;
    for (; e + 8 <= e1; e += 8) {
        int s[8]; float at[8]; uint32_t ea[8];
#pragma unroll
        for (int u = 0; u < 8; ++u) s[u] = srcp[e + u];
#pragma unroll
        for (int u = 0; u < 8; ++u) at[u] = attp[e + u];
#pragma unroll
        for (int u = 0; u < 8; ++u) ea[u] = eab[(size_t)(e + u) * 64 + lane];
        float2 hv[8];
#pragma unroll
        for (int u = 0; u < 8; ++u)
            hv[u] = *(const float2*)&h[(size_t)s[u] * 128 + c];
#pragma unroll
        for (int u = 0; u < 8; ++u) {
            const __half2 hh = *reinterpret_cast<const __half2*>(&ea[u]);
            const float ex = __half2float(__low2half(hh));
            const float ey = __half2float(__high2half(hh));
            a0 += fmaxf(hv[u].x + ex, 0.f) * at[u];
            a1 += fmaxf(hv[u].y + ey, 0.f) * at[u];
        }
    }
    for (; e < e1; ++e) {
        const int s = srcp[e];
        const float at = attp[e];
        const uint32_t ea = eab[(size_t)e * 64 + lane];
        const float2 hv = *(const float2*)&h[(size_t)s * 128 + c];
        const __half2 hh = *reinterpret_cast<const __half2*>(&ea);
        a0 += fmaxf(hv.x + __half2float(__low2half(hh)), 0.f) * at;
        a1 += fmaxf(hv.y + __half2float(__high2half(hh)), 0.f) * at;
    }

    const float sc = 1.0f + eps[layer];
    const float2 hv = *(const float2*)&h[(size_t)v * 128 + c];
    float2 z;
    z.x = fmaf(sc, hv.x, a0);
    z.y = fmaf(sc, hv.y, a1);
    *(float2*)&Z[(size_t)v * 128 + c] = z;
}

// ---------------------------------------------------------------------------
// Aggregation fallback (round-4 style): W_ee in regs, 4-edge unroll.
// EA=true: f32 ea rows pre-permuted; else gather via eids.
// ---------------------------------------------------------------------------
template <bool EA>
__global__ __launch_bounds__(256) void agg_gather(
    const float* __restrict__ h, const int* __restrict__ srcp,
    const float* __restrict__ attp, const float4* __restrict__ eap,
    const int* __restrict__ eids, const float* __restrict__ eattr,
    const int* __restrict__ off,
    const float* __restrict__ W_ee, const float* __restrict__ b_ee,
    float* __restrict__ Z, const float* __restrict__ eps, int layer, int N)
{
    const int t = threadIdx.x;
    const int lane = t & 63;
    const int c = lane * 2;
    float2 w[16];
#pragma unroll
    for (int k = 0; k < 16; ++k) w[k] = *(const float2*)&W_ee[k * 128 + c];
    const float2 bv = *(const float2*)&b_ee[c];

    const int v = blockIdx.x * 4 + (t >> 6);
    if (v >= N) return;

    const int e0 = off[v], e1 = off[v + 1];
    float a0 = 0.f, a1 = 0.f;
    int e = e0;
    for (; e + 4 <= e1; e += 4) {
        int s[4]; float at[4];
#pragma unroll
        for (int u = 0; u < 4; ++u) { s[u] = srcp[e + u]; at[u] = attp[e + u]; }
        float2 hv[4];
#pragma unroll
        for (int u = 0; u < 4; ++u)
            hv[u] = *(const float2*)&h[(size_t)s[u] * 128 + c];
        float4 ev[4][4];
#pragma unroll
        for (int u = 0; u < 4; ++u) {
            const float4* e4;
            if constexpr (EA) e4 = eap + (size_t)(e + u) * 4;
            else e4 = (const float4*)(eattr + (size_t)eids[e + u] * 16);
#pragma unroll
            for (int q = 0; q < 4; ++q) ev[u][q] = e4[q];
        }
#pragma unroll
        for (int u = 0; u < 4; ++u) {
            const float* ef = (const float*)&ev[u][0];
            float d0 = bv.x, d1 = bv.y;
#pragma unroll
            for (int k = 0; k < 16; ++k) {
                d0 = fmaf(ef[k], w[k].x, d0);
                d1 = fmaf(ef[k], w[k].y, d1);
            }
            a0 += fmaxf(hv[u].x + d0, 0.f) * at[u];
            a1 += fmaxf(hv[u].y + d1, 0.f) * at[u];
        }
    }
    for (; e < e1; ++e) {
        const int s = srcp[e];
        const float at = attp[e];
        const float2 hv = *(const float2*)&h[(size_t)s * 128 + c];
        const float4* e4;
        if constexpr (EA) e4 = eap + (size_t)e * 4;
        else e4 = (const float4*)(eattr + (size_t)eids[e] * 16);
        float4 ev[4];
#pragma unroll
        for (int q = 0; q < 4; ++q) ev[q] = e4[q];
        const float* ef = (const float*)&ev[0];
        float d0 = bv.x, d1 = bv.y;
#pragma unroll
        for (int k = 0; k < 16; ++k) {
            d0 = fmaf(ef[k], w[k].x, d0);
            d1 = fmaf(ef[k], w[k].y, d1);
        }
        a0 += fmaxf(hv.x + d0, 0.f) * at;
        a1 += fmaxf(hv.y + d1, 0.f) * at;
    }

    const float sc = 1.0f + eps[layer];
    const float2 hv = *(const float2*)&h[(size_t)v * 128 + c];
    float2 z;
    z.x = fmaf(sc, hv.x, a0);
    z.y = fmaf(sc, hv.y, a1);
    *(float2*)&Z[(size_t)v * 128 + c] = z;
}

// ---------------------------------------------------------------------------
// Encoder GEMM: h = A@W + b.  512 thr, 64-row tile, W double-buffered.
// ---------------------------------------------------------------------------
__global__ __launch_bounds__(512, 4) void gemm_enc(
    const float* __restrict__ A, const float* __restrict__ W,
    const float* __restrict__ bias, float* __restrict__ H, int n)
{
    __shared__ float At[64][128];
    __shared__ float Wb[2][16][128];
    const int t = threadIdx.x;
    const int tx = t & 31, ty = t >> 5;

    const int row0 = blockIdx.x * 64;
    const int nrows = min(64, n - row0);
    const int lim = nrows * 32;
    const float4* A4 = (const float4*)(A + (size_t)row0 * 128);
    float4* At4 = (float4*)&At[0][0];
#pragma unroll
    for (int i = 0; i < 4; ++i) {
        int idx = t + 512 * i;
        if (idx < lim) At4[idx] = A4[idx];
    }
    const float4* W4 = (const float4*)W;
    ((float4*)&Wb[0][0][0])[t] = W4[t];
    __syncthreads();

    float acc[4][4] = {};
    for (int c = 0; c < 8; ++c) {
        const int buf = c & 1;
        float4 wnext;
        if (c < 7) wnext = W4[(c + 1) * 512 + t];
#pragma unroll
        for (int g = 0; g < 4; ++g) {
            float4 w4[4];
#pragma unroll
            for (int kk = 0; kk < 4; ++kk) w4[kk] = *(const float4*)&Wb[buf][g * 4 + kk][tx * 4];
#pragma unroll
            for (int r = 0; r < 4; ++r) {
                float4 a = *(const float4*)&At[ty * 4 + r][c * 16 + g * 4];
                float ar[4] = {a.x, a.y, a.z, a.w};
#pragma unroll
                for (int kk = 0; kk < 4; ++kk) {
                    acc[r][0] = fmaf(ar[kk], w4[kk].x, acc[r][0]);
                    acc[r][1] = fmaf(ar[kk], w4[kk].y, acc[r][1]);
                    acc[r][2] = fmaf(ar[kk], w4[kk].z, acc[r][2]);
                    acc[r][3] = fmaf(ar[kk], w4[kk].w, acc[r][3]);
                }
            }
        }
        if (c < 7) ((float4*)&Wb[buf ^ 1][0][0])[t] = wnext;
        __syncthreads();
    }

    const int c0 = tx * 4;
    float bvv[4];
#pragma unroll
    for (int c = 0; c < 4; ++c) bvv[c] = bias[c0 + c];
#pragma unroll
    for (int r = 0; r < 4; ++r) {
        int row = row0 + ty * 4 + r;
        if (row < n) {
            float4 o;
            o.x = acc[r][0] + bvv[0]; o.y = acc[r][1] + bvv[1];
            o.z = acc[r][2] + bvv[2]; o.w = acc[r][3] + bvv[3];
            *(float4*)&H[(size_t)row * 128 + c0] = o;
        }
    }
}

// ---------------------------------------------------------------------------
// Fused MLP: h = relu( relu(BN(Z@W1+b1)) @ W2 + b2 ).
// ---------------------------------------------------------------------------
__global__ __launch_bounds__(512, 4) void gemm_mlp(
    const float* __restrict__ Z,
    const float* __restrict__ W1, const float* __restrict__ b1,
    const float* __restrict__ gam, const float* __restrict__ bet,
    const float* __restrict__ mu, const float* __restrict__ var,
    const float* __restrict__ W2, const float* __restrict__ b2,
    float* __restrict__ H, int n)
{
    __shared__ float At[64][128];
    __shared__ float Wb[2][16][128];
    const int t = threadIdx.x;
    const int tx = t & 31, ty = t >> 5;

    const int row0 = blockIdx.x * 64;
    const int nrows = min(64, n - row0);
    const int lim = nrows * 32;
    const float4* Z4 = (const float4*)(Z + (size_t)row0 * 128);
    float4* At4 = (float4*)&At[0][0];
#pragma unroll
    for (int i = 0; i < 4; ++i) {
        int idx = t + 512 * i;
        if (idx < lim) At4[idx] = Z4[idx];
    }
    const float4* W14 = (const float4*)W1;
    ((float4*)&Wb[0][0][0])[t] = W14[t];
    __syncthreads();

    float acc[4][4] = {};
    for (int c = 0; c < 8; ++c) {
        const int buf = c & 1;
        float4 wnext;
        if (c < 7) wnext = W14[(c + 1) * 512 + t];
#pragma unroll
        for (int g = 0; g < 4; ++g) {
            float4 w4[4];
#pragma unroll
            for (int kk = 0; kk < 4; ++kk) w4[kk] = *(const float4*)&Wb[buf][g * 4 + kk][tx * 4];
#pragma unroll
            for (int r = 0; r < 4; ++r) {
                float4 a = *(const float4*)&At[ty * 4 + r][c * 16 + g * 4];
                float ar[4] = {a.x, a.y, a.z, a.w};
#pragma unroll
                for (int kk = 0; kk < 4; ++kk) {
                    acc[r][0] = fmaf(ar[kk], w4[kk].x, acc[r][0]);
                    acc[r][1] = fmaf(ar[kk], w4[kk].y, acc[r][1]);
                    acc[r][2] = fmaf(ar[kk], w4[kk].z, acc[r][2]);
                    acc[r][3] = fmaf(ar[kk], w4[kk].w, acc[r][3]);
                }
            }
        }
        if (c < 7) ((float4*)&Wb[buf ^ 1][0][0])[t] = wnext;
        __syncthreads();
    }

    const int c0 = tx * 4;
    const float4* W24 = (const float4*)W2;
    float4 w2pre = W24[t];
    {
        float b1v[4], sc[4], sh[4];
#pragma unroll
        for (int c = 0; c < 4; ++c) {
            b1v[c] = b1[c0 + c];
            float s = gam[c0 + c] * rsqrtf(var[c0 + c] + 1e-5f);
            sc[c] = s;
            sh[c] = bet[c0 + c] - mu[c0 + c] * s;
        }
#pragma unroll
        for (int r = 0; r < 4; ++r) {
            float4 y;
            y.x = fmaxf(fmaf(acc[r][0] + b1v[0], sc[0], sh[0]), 0.f);
            y.y = fmaxf(fmaf(acc[r][1] + b1v[1], sc[1], sh[1]), 0.f);
            y.z = fmaxf(fmaf(acc[r][2] + b1v[2], sc[2], sh[2]), 0.f);
            y.w = fmaxf(fmaf(acc[r][3] + b1v[3], sc[3], sh[3]), 0.f);
            *(float4*)&At[ty * 4 + r][c0] = y;
            acc[r][0] = 0.f; acc[r][1] = 0.f; acc[r][2] = 0.f; acc[r][3] = 0.f;
        }
    }
    ((float4*)&Wb[0][0][0])[t] = w2pre;
    __syncthreads();

    for (int c = 0; c < 8; ++c) {
        const int buf = c & 1;
        float4 wnext;
        if (c < 7) wnext = W24[(c + 1) * 512 + t];
#pragma unroll
        for (int g = 0; g < 4; ++g) {
            float4 w4[4];
#pragma unroll
            for (int kk = 0; kk < 4; ++kk) w4[kk] = *(const float4*)&Wb[buf][g * 4 + kk][tx * 4];
#pragma unroll
            for (int r = 0; r < 4; ++r) {
                float4 a = *(const float4*)&At[ty * 4 + r][c * 16 + g * 4];
                float ar[4] = {a.x, a.y, a.z, a.w};
#pragma unroll
                for (int kk = 0; kk < 4; ++kk) {
                    acc[r][0] = fmaf(ar[kk], w4[kk].x, acc[r][0]);
                    acc[r][1] = fmaf(ar[kk], w4[kk].y, acc[r][1]);
                    acc[r][2] = fmaf(ar[kk], w4[kk].z, acc[r][2]);
                    acc[r][3] = fmaf(ar[kk], w4[kk].w, acc[r][3]);
                }
            }
        }
        if (c < 7) ((float4*)&Wb[buf ^ 1][0][0])[t] = wnext;
        __syncthreads();
    }

    float b2v[4];
#pragma unroll
    for (int c = 0; c < 4; ++c) b2v[c] = b2[c0 + c];
#pragma unroll
    for (int r = 0; r < 4; ++r) {
        int row = row0 + ty * 4 + r;
        if (row < n) {
            float4 o;
            o.x = fmaxf(acc[r][0] + b2v[0], 0.f);
            o.y = fmaxf(acc[r][1] + b2v[1], 0.f);
            o.z = fmaxf(acc[r][2] + b2v[2], 0.f);
            o.w = fmaxf(acc[r][3] + b2v[3], 0.f);
            *(float4*)&H[(size_t)row * 128 + c0] = o;
        }
    }
}

// ---------------------------------------------------------------------------
// Last-resort fallback: scale_init + atomic edge kernel
// ---------------------------------------------------------------------------
__global__ void scale_init(const float* __restrict__ h, float* __restrict__ z,
                           const float* __restrict__ eps, int layer, int n4)
{
    const float s = 1.0f + eps[layer];
    int i = blockIdx.x * blockDim.x + threadIdx.x;
    const int stride = gridDim.x * blockDim.x;
    const float4* h4 = (const float4*)h;
    float4* z4 = (float4*)z;
    for (; i < n4; i += stride) {
        float4 v = h4[i];
        v.x *= s; v.y *= s; v.z *= s; v.w *= s;
        z4[i] = v;
    }
}

__global__ __launch_bounds__(256) void edge_atomic(
    const float* __restrict__ h, const int* __restrict__ ei,
    const float* __restrict__ eattr, const float* __restrict__ eatten,
    const float* __restrict__ W_ee, const float* __restrict__ b_ee,
    float* __restrict__ Z, int E)
{
    __shared__ float Wee[16][128];
    __shared__ float bee[128];
    const int t = threadIdx.x;
    const float4* We4 = (const float4*)W_ee;
    float4* Ws4 = (float4*)&Wee[0][0];
#pragma unroll
    for (int i = 0; i < 2; ++i) Ws4[t + 256 * i] = We4[t + 256 * i];
    if (t < 128) bee[t] = b_ee[t];
    __syncthreads();

    const int lane = t & 63;
    const int c = lane * 2;
    const long wid = (long)blockIdx.x * 4 + (t >> 6);
    const long nw = (long)gridDim.x * 4;
    for (long e = wid; e < E; e += nw) {
        const int src = ei[e];
        const int dst = ei[E + e];
        const float att = eatten[e];
        union { float4 v4[4]; float f[16]; } ea;
        const float4* eap = (const float4*)(eattr + e * 16);
        ea.v4[0] = eap[0]; ea.v4[1] = eap[1]; ea.v4[2] = eap[2]; ea.v4[3] = eap[3];
        float2 hv = *(const float2*)&h[(size_t)src * 128 + c];
        float e0 = bee[c], e1 = bee[c + 1];
#pragma unroll
        for (int k = 0; k < 16; ++k) {
            float2 w = *(const float2*)&Wee[k][c];
            e0 = fmaf(ea.f[k], w.x, e0);
            e1 = fmaf(ea.f[k], w.y, e1);
        }
        float m0 = fmaxf(hv.x + e0, 0.f) * att;
        float m1 = fmaxf(hv.y + e1, 0.f) * att;
        atomic_add2(&Z[(size_t)dst * 128 + c], m0, m1);
    }
}

extern "C" void kernel_launch(void* const* d_in, const int* in_sizes, int n_in,
                              void* d_out, int out_size, void* d_ws, size_t ws_size,
                              hipStream_t stream)
{
    const float* x      = (const float*)d_in[0];
    const int*   ei     = (const int*)d_in[1];
    // d_in[2] = batch (unused)
    const float* eattr  = (const float*)d_in[3];
    const float* eatten = (const float*)d_in[4];
    const float* W_enc  = (const float*)d_in[5];
    const float* b_enc  = (const float*)d_in[6];
    const float* W_ee   = (const float*)d_in[7];
    const float* b_ee   = (const float*)d_in[8];
    const float* eps    = (const float*)d_in[9];
    const float* W1     = (const float*)d_in[10];
    const float* b1     = (const float*)d_in[11];
    const float* gam    = (const float*)d_in[12];
    const float* bet    = (const float*)d_in[13];
    const float* mu     = (const float*)d_in[14];
    const float* var    = (const float*)d_in[15];
    const float* W2     = (const float*)d_in[16];
    const float* b2     = (const float*)d_in[17];

    const int N = in_sizes[0] / 128;
    const int E = in_sizes[1] / 2;
    const int L = in_sizes[9];

    float* h = (float*)d_out;   // [N,128]

    // workspace layout
    char* p = (char*)d_ws;
    float* zbuf = (float*)p;            p += ((size_t)N * 128 * 4 + 255) & ~(size_t)255;
    int* off  = (int*)p;                p += 4 * (size_t)(N + 1);
    int* cur  = (int*)p;                p += 4 * (size_t)N;
    int* cnt  = (int*)p;                p += 4 * (size_t)N;
    int* eids = (int*)p;                p += 4 * (size_t)E;
    const size_t need_csr = (size_t)(p - (char*)d_ws);
    int*   srcp = (int*)p;              p += 4 * (size_t)E;
    float* attp = (float*)p;            p += 4 * (size_t)E;
    const size_t need_perm = (size_t)(p - (char*)d_ws);
    p = (char*)(((uintptr_t)p + 15) & ~(uintptr_t)15);
    // overlapping region: either f32 eap (64 B/edge) or f16 eab (256 B/edge)
    float4*   eap = (float4*)p;
    uint32_t* eab = (uint32_t*)p;
    const size_t need_eaf32 = (size_t)(p - (char*)d_ws) + 64  * (size_t)E;
    const size_t need_eaf16 = (size_t)(p - (char*)d_ws) + 256 * (size_t)E;

    const bool use_csr  = ws_size >= need_csr;
    const bool use_perm = ws_size >= need_perm;
    const bool use_ea32 = ws_size >= need_eaf32;
    const bool use_ea16 = ws_size >= need_eaf16;

    const int tiles = (N + 63) / 64;

    gemm_enc<<<tiles, 512, 0, stream>>>(x, W_enc, b_enc, h, N);

    if (use_csr) {
        zero_cnt<<<(N + 255) / 256, 256, 0, stream>>>(cnt, N);
        hist_kernel<<<1024, 256, 0, stream>>>(ei, cnt, E);
        scan_kernel<<<1, 1024, 0, stream>>>(cnt, off, cur, N, E);
        scatter_kernel<<<1024, 256, 0, stream>>>(ei, cur, eids, E);
        if (use_perm)
            permute_kernel<<<1024, 256, 0, stream>>>(ei, eatten, eids, srcp, attp, E);
        if (use_ea16)
            eabuild_kernel<<<2048, 256, 0, stream>>>(eids, eattr, W_ee, b_ee, eab, E);
        else if (use_ea32) {
            // build f32 ea rows in slot order via the f16 builder's logic is not
            // applicable; reuse agg_gather<false> path instead (no prebuild).
        }
    }

    for (int i = 0; i < L; ++i) {
        if (use_ea16) {
            agg_f16<<<(N + 3) / 4, 256, 0, stream>>>(
                h, srcp, attp, eab, off, zbuf, eps, i, N);
        } else if (use_perm) {
            agg_gather<false><<<(N + 3) / 4, 256, 0, stream>>>(
                h, srcp, attp, eap, eids, eattr, off, W_ee, b_ee, zbuf, eps, i, N);
        } else if (use_csr) {
            // no srcp/attp: fall back to atomic path (agg_gather needs perm arrays)
            scale_init<<<2048, 256, 0, stream>>>(h, zbuf, eps, i, N * 128 / 4);
            edge_atomic<<<2048, 256, 0, stream>>>(h, ei, eattr, eatten, W_ee, b_ee, zbuf, E);
        } else {
            scale_init<<<2048, 256, 0, stream>>>(h, zbuf, eps, i, N * 128 / 4);
            edge_atomic<<<2048, 256, 0, stream>>>(h, ei, eattr, eatten, W_ee, b_ee, zbuf, E);
        }
        gemm_mlp<<<tiles, 512, 0, stream>>>(
            zbuf, W1 + (size_t)i * 128 * 128, b1 + i * 128,
            gam + i * 128, bet + i * 128, mu + i * 128, var + i * 128,
            W2 + (size_t)i * 128 * 128, b2 + i * 128,
            h, N);
    }
}

// Round 6
// 914.186 us; speedup vs baseline: 1.1950x; 1.1950x over previous
//
#include <hip/hip_runtime.h>
#include <hip/hip_fp16.h>
#include <cstdint>
#include <cstddef>

// ---------------------------------------------------------------------------
// GIN (GINEConv x3) forward, f32.
//   h  = x@W_enc + b_enc                                  (gemm_enc)
//   CSR build: hist -> scan -> scatter -> permute(srcp,attp) -> eabuild(f16)
//   per layer i:
//     agg:  z[v] = (1+eps_i) h[v] + sum_{e: dst=v} relu(h[src_e]+ea_e)*att_e
//           one wave per node, ea precomputed f16, 8-edge unrolled gather
//     mlp:  h = relu( relu(BN(z@W1+b1)) @ W2 + b2 )       (gemm_mlp fused)
// ---------------------------------------------------------------------------

// ---- packed-f32x2 atomic with compile-safe fallback (fallback path only) ---
template <class T>
__device__ inline auto add2_impl(T* p, T v, int)
    -> decltype(unsafeAtomicAdd(p, v), void()) {
    unsafeAtomicAdd(p, v);
}
template <class T>
__device__ inline void add2_impl(T* p, T v, long) {
    unsafeAtomicAdd(&p->x, v.x);
    unsafeAtomicAdd(&p->y, v.y);
}
__device__ inline void atomic_add2(float* p, float x, float y) {
    add2_impl(reinterpret_cast<float2*>(p), make_float2(x, y), 0);
}

// ---------------------------------------------------------------------------
// CSR build
// ---------------------------------------------------------------------------
__global__ void zero_cnt(int* __restrict__ cnt, int N)
{
    int i = blockIdx.x * blockDim.x + threadIdx.x;
    if (i < N) cnt[i] = 0;
}

__global__ void hist_kernel(const int* __restrict__ ei, int* __restrict__ cnt, int E)
{
    int i = blockIdx.x * blockDim.x + threadIdx.x;
    const int st = gridDim.x * blockDim.x;
    for (; i < E; i += st) atomicAdd(&cnt[ei[E + i]], 1);
}

// single-block exclusive scan of cnt[0..N) -> off, cur ; off[N]=E
__global__ __launch_bounds__(1024) void scan_kernel(
    const int* __restrict__ cnt, int* __restrict__ off, int* __restrict__ cur,
    int N, int E)
{
    __shared__ int part[1024];
    const int t = threadIdx.x;
    const int chunk = (N + 1023) / 1024;
    const int s0 = min(t * chunk, N), s1 = min(s0 + chunk, N);
    int sum = 0;
    for (int i = s0; i < s1; ++i) sum += cnt[i];
    part[t] = sum;
    __syncthreads();
    for (int d = 1; d < 1024; d <<= 1) {
        int v = (t >= d) ? part[t - d] : 0;
        __syncthreads();
        part[t] += v;
        __syncthreads();
    }
    int base = (t == 0) ? 0 : part[t - 1];
    for (int i = s0; i < s1; ++i) {
        off[i] = base; cur[i] = base;
        base += cnt[i];
    }
    if (t == 0) off[N] = E;
}

__global__ void scatter_kernel(const int* __restrict__ ei, int* __restrict__ cur,
                               int* __restrict__ eids, int E)
{
    int i = blockIdx.x * blockDim.x + threadIdx.x;
    const int st = gridDim.x * blockDim.x;
    for (; i < E; i += st) {
        int pos = atomicAdd(&cur[ei[E + i]], 1);
        eids[pos] = i;
    }
}

// permute src/att into CSR slot order
__global__ void permute_kernel(
    const int* __restrict__ ei, const float* __restrict__ eatten,
    const int* __restrict__ eids,
    int* __restrict__ srcp, float* __restrict__ attp, int E)
{
    int i = blockIdx.x * blockDim.x + threadIdx.x;
    const int st = gridDim.x * blockDim.x;
    for (; i < E; i += st) {
        const int eid = eids[i];
        srcp[i] = ei[eid];
        attp[i] = eatten[eid];
    }
}

// ---------------------------------------------------------------------------
// eabuild (staged): ea = edge_attr@W_ee + b_ee in CSR slot order, packed half2.
// One block per 256 slots:
//   phase 1: eids -> LDS (coalesced)
//   phase 2: gather 256 eattr rows -> LDS (1024 independent float4 loads)
//   phase 3: each wave computes 64 slots from LDS, coalesced 256B stores
// ---------------------------------------------------------------------------
__global__ __launch_bounds__(256) void eabuild_staged(
    const int* __restrict__ eids, const float* __restrict__ eattr,
    const float* __restrict__ W_ee, const float* __restrict__ b_ee,
    uint32_t* __restrict__ eab, int E)
{
    __shared__ int   se[256];          // 1 KB
    __shared__ float sattr[256 * 16];  // 16 KB
    const int t = threadIdx.x;
    const int lane = t & 63;
    const int wv = t >> 6;
    const int c = lane * 2;

    // per-lane weight slice (2 cols)
    float2 w[16];
#pragma unroll
    for (int k = 0; k < 16; ++k) w[k] = *(const float2*)&W_ee[k * 128 + c];
    const float2 bv = *(const float2*)&b_ee[c];

    const int base = blockIdx.x * 256;
    const int n = min(256, E - base);
    if (n <= 0) return;

    if (t < n) se[t] = eids[base + t];
    __syncthreads();

    // gather eattr rows: n*4 independent float4 loads
    float4* sa4 = (float4*)sattr;
    const float4* ea4 = (const float4*)eattr;
    for (int i = t; i < n * 4; i += 256) {
        const int row = i >> 2, part = i & 3;
        sa4[i] = ea4[(size_t)se[row] * 4 + part];
    }
    __syncthreads();

    // compute: wave wv handles slots wv, wv+4, ...
    for (int slot = wv; slot < n; slot += 4) {
        const float4* sr = (const float4*)&sattr[slot * 16];
        float4 e0 = sr[0], e1 = sr[1], e2 = sr[2], e3 = sr[3];
        const float ef[16] = {e0.x, e0.y, e0.z, e0.w, e1.x, e1.y, e1.z, e1.w,
                              e2.x, e2.y, e2.z, e2.w, e3.x, e3.y, e3.z, e3.w};
        float d0 = bv.x, d1 = bv.y;
#pragma unroll
        for (int k = 0; k < 16; ++k) {
            d0 = fmaf(ef[k], w[k].x, d0);
            d1 = fmaf(ef[k], w[k].y, d1);
        }
        __half2 hh = __floats2half2_rn(d0, d1);
        eab[(size_t)(base + slot) * 64 + lane] = *reinterpret_cast<uint32_t*>(&hh);
    }
}

// ---------------------------------------------------------------------------
// Aggregation (f16-ea tier): one wave per node, lane owns 2 cols.
// ---------------------------------------------------------------------------
__global__ __launch_bounds__(256) void agg_f16(
    const float* __restrict__ h, const int* __restrict__ srcp,
    const float* __restrict__ attp, const uint32_t* __restrict__ eab,
    const int* __restrict__ off,
    float* __restrict__ Z, const float* __restrict__ eps, int layer, int N)
{
    const int t = threadIdx.x;
    const int v = blockIdx.x * 4 + (t >> 6);
    if (v >= N) return;
    const int lane = t & 63;
    const int c = lane * 2;

    const int e0 = off[v], e1 = off[v + 1];
    float a0 = 0.f, a1 = 0.f;
    int e = e0;
    for (; e + 8 <= e1; e += 8) {
        int s[8]; float at[8]; uint32_t ea[8];
#pragma unroll
        for (int u = 0; u < 8; ++u) s[u] = srcp[e + u];
#pragma unroll
        for (int u = 0; u < 8; ++u) at[u] = attp[e + u];
#pragma unroll
        for (int u = 0; u < 8; ++u) ea[u] = eab[(size_t)(e + u) * 64 + lane];
        float2 hv[8];
#pragma unroll
        for (int u = 0; u < 8; ++u)
            hv[u] = *(const float2*)&h[(size_t)s[u] * 128 + c];
#pragma unroll
        for (int u = 0; u < 8; ++u) {
            const __half2 hh = *reinterpret_cast<const __half2*>(&ea[u]);
            const float ex = __half2float(__low2half(hh));
            const float ey = __half2float(__high2half(hh));
            a0 += fmaxf(hv[u].x + ex, 0.f) * at[u];
            a1 += fmaxf(hv[u].y + ey, 0.f) * at[u];
        }
    }
    for (; e < e1; ++e) {
        const int s = srcp[e];
        const float at = attp[e];
        const uint32_t ea = eab[(size_t)e * 64 + lane];
        const float2 hv = *(const float2*)&h[(size_t)s * 128 + c];
        const __half2 hh = *reinterpret_cast<const __half2*>(&ea);
        a0 += fmaxf(hv.x + __half2float(__low2half(hh)), 0.f) * at;
        a1 += fmaxf(hv.y + __half2float(__high2half(hh)), 0.f) * at;
    }

    const float sc = 1.0f + eps[layer];
    const float2 hv = *(const float2*)&h[(size_t)v * 128 + c];
    float2 z;
    z.x = fmaf(sc, hv.x, a0);
    z.y = fmaf(sc, hv.y, a1);
    *(float2*)&Z[(size_t)v * 128 + c] = z;
}

// ---------------------------------------------------------------------------
// Aggregation fallback (round-4 style): W_ee in regs, 4-edge unroll.
// ---------------------------------------------------------------------------
template <bool EA>
__global__ __launch_bounds__(256) void agg_gather(
    const float* __restrict__ h, const int* __restrict__ srcp,
    const float* __restrict__ attp, const float4* __restrict__ eap,
    const int* __restrict__ eids, const float* __restrict__ eattr,
    const int* __restrict__ off,
    const float* __restrict__ W_ee, const float* __restrict__ b_ee,
    float* __restrict__ Z, const float* __restrict__ eps, int layer, int N)
{
    const int t = threadIdx.x;
    const int lane = t & 63;
    const int c = lane * 2;
    float2 w[16];
#pragma unroll
    for (int k = 0; k < 16; ++k) w[k] = *(const float2*)&W_ee[k * 128 + c];
    const float2 bv = *(const float2*)&b_ee[c];

    const int v = blockIdx.x * 4 + (t >> 6);
    if (v >= N) return;

    const int e0 = off[v], e1 = off[v + 1];
    float a0 = 0.f, a1 = 0.f;
    int e = e0;
    for (; e + 4 <= e1; e += 4) {
        int s[4]; float at[4];
#pragma unroll
        for (int u = 0; u < 4; ++u) { s[u] = srcp[e + u]; at[u] = attp[e + u]; }
        float2 hv[4];
#pragma unroll
        for (int u = 0; u < 4; ++u)
            hv[u] = *(const float2*)&h[(size_t)s[u] * 128 + c];
        float4 ev[4][4];
#pragma unroll
        for (int u = 0; u < 4; ++u) {
            const float4* e4;
            if constexpr (EA) e4 = eap + (size_t)(e + u) * 4;
            else e4 = (const float4*)(eattr + (size_t)eids[e + u] * 16);
#pragma unroll
            for (int q = 0; q < 4; ++q) ev[u][q] = e4[q];
        }
#pragma unroll
        for (int u = 0; u < 4; ++u) {
            const float* ef = (const float*)&ev[u][0];
            float d0 = bv.x, d1 = bv.y;
#pragma unroll
            for (int k = 0; k < 16; ++k) {
                d0 = fmaf(ef[k], w[k].x, d0);
                d1 = fmaf(ef[k], w[k].y, d1);
            }
            a0 += fmaxf(hv[u].x + d0, 0.f) * at[u];
            a1 += fmaxf(hv[u].y + d1, 0.f) * at[u];
        }
    }
    for (; e < e1; ++e) {
        const int s = srcp[e];
        const float at = attp[e];
        const float2 hv = *(const float2*)&h[(size_t)s * 128 + c];
        const float4* e4;
        if constexpr (EA) e4 = eap + (size_t)e * 4;
        else e4 = (const float4*)(eattr + (size_t)eids[e] * 16);
        float4 ev[4];
#pragma unroll
        for (int q = 0; q < 4; ++q) ev[q] = e4[q];
        const float* ef = (const float*)&ev[0];
        float d0 = bv.x, d1 = bv.y;
#pragma unroll
        for (int k = 0; k < 16; ++k) {
            d0 = fmaf(ef[k], w[k].x, d0);
            d1 = fmaf(ef[k], w[k].y, d1);
        }
        a0 += fmaxf(hv.x + d0, 0.f) * at;
        a1 += fmaxf(hv.y + d1, 0.f) * at;
    }

    const float sc = 1.0f + eps[layer];
    const float2 hv = *(const float2*)&h[(size_t)v * 128 + c];
    float2 z;
    z.x = fmaf(sc, hv.x, a0);
    z.y = fmaf(sc, hv.y, a1);
    *(float2*)&Z[(size_t)v * 128 + c] = z;
}

// ---------------------------------------------------------------------------
// Encoder GEMM: h = A@W + b.  512 thr, 64-row tile, W double-buffered.
// ---------------------------------------------------------------------------
__global__ __launch_bounds__(512, 4) void gemm_enc(
    const float* __restrict__ A, const float* __restrict__ W,
    const float* __restrict__ bias, float* __restrict__ H, int n)
{
    __shared__ float At[64][128];
    __shared__ float Wb[2][16][128];
    const int t = threadIdx.x;
    const int tx = t & 31, ty = t >> 5;

    const int row0 = blockIdx.x * 64;
    const int nrows = min(64, n - row0);
    const int lim = nrows * 32;
    const float4* A4 = (const float4*)(A + (size_t)row0 * 128);
    float4* At4 = (float4*)&At[0][0];
#pragma unroll
    for (int i = 0; i < 4; ++i) {
        int idx = t + 512 * i;
        if (idx < lim) At4[idx] = A4[idx];
    }
    const float4* W4 = (const float4*)W;
    ((float4*)&Wb[0][0][0])[t] = W4[t];
    __syncthreads();

    float acc[4][4] = {};
    for (int c = 0; c < 8; ++c) {
        const int buf = c & 1;
        float4 wnext;
        if (c < 7) wnext = W4[(c + 1) * 512 + t];
#pragma unroll
        for (int g = 0; g < 4; ++g) {
            float4 w4[4];
#pragma unroll
            for (int kk = 0; kk < 4; ++kk) w4[kk] = *(const float4*)&Wb[buf][g * 4 + kk][tx * 4];
#pragma unroll
            for (int r = 0; r < 4; ++r) {
                float4 a = *(const float4*)&At[ty * 4 + r][c * 16 + g * 4];
                float ar[4] = {a.x, a.y, a.z, a.w};
#pragma unroll
                for (int kk = 0; kk < 4; ++kk) {
                    acc[r][0] = fmaf(ar[kk], w4[kk].x, acc[r][0]);
                    acc[r][1] = fmaf(ar[kk], w4[kk].y, acc[r][1]);
                    acc[r][2] = fmaf(ar[kk], w4[kk].z, acc[r][2]);
                    acc[r][3] = fmaf(ar[kk], w4[kk].w, acc[r][3]);
                }
            }
        }
        if (c < 7) ((float4*)&Wb[buf ^ 1][0][0])[t] = wnext;
        __syncthreads();
    }

    const int c0 = tx * 4;
    float bvv[4];
#pragma unroll
    for (int c = 0; c < 4; ++c) bvv[c] = bias[c0 + c];
#pragma unroll
    for (int r = 0; r < 4; ++r) {
        int row = row0 + ty * 4 + r;
        if (row < n) {
            float4 o;
            o.x = acc[r][0] + bvv[0]; o.y = acc[r][1] + bvv[1];
            o.z = acc[r][2] + bvv[2]; o.w = acc[r][3] + bvv[3];
            *(float4*)&H[(size_t)row * 128 + c0] = o;
        }
    }
}

// ---------------------------------------------------------------------------
// Fused MLP: h = relu( relu(BN(Z@W1+b1)) @ W2 + b2 ).
// ---------------------------------------------------------------------------
__global__ __launch_bounds__(512, 4) void gemm_mlp(
    const float* __restrict__ Z,
    const float* __restrict__ W1, const float* __restrict__ b1,
    const float* __restrict__ gam, const float* __restrict__ bet,
    const float* __restrict__ mu, const float* __restrict__ var,
    const float* __restrict__ W2, const float* __restrict__ b2,
    float* __restrict__ H, int n)
{
    __shared__ float At[64][128];
    __shared__ float Wb[2][16][128];
    const int t = threadIdx.x;
    const int tx = t & 31, ty = t >> 5;

    const int row0 = blockIdx.x * 64;
    const int nrows = min(64, n - row0);
    const int lim = nrows * 32;
    const float4* Z4 = (const float4*)(Z + (size_t)row0 * 128);
    float4* At4 = (float4*)&At[0][0];
#pragma unroll
    for (int i = 0; i < 4; ++i) {
        int idx = t + 512 * i;
        if (idx < lim) At4[idx] = Z4[idx];
    }
    const float4* W14 = (const float4*)W1;
    ((float4*)&Wb[0][0][0])[t] = W14[t];
    __syncthreads();

    float acc[4][4] = {};
    for (int c = 0; c < 8; ++c) {
        const int buf = c & 1;
        float4 wnext;
        if (c < 7) wnext = W14[(c + 1) * 512 + t];
#pragma unroll
        for (int g = 0; g < 4; ++g) {
            float4 w4[4];
#pragma unroll
            for (int kk = 0; kk < 4; ++kk) w4[kk] = *(const float4*)&Wb[buf][g * 4 + kk][tx * 4];
#pragma unroll
            for (int r = 0; r < 4; ++r) {
                float4 a = *(const float4*)&At[ty * 4 + r][c * 16 + g * 4];
                float ar[4] = {a.x, a.y, a.z, a.w};
#pragma unroll
                for (int kk = 0; kk < 4; ++kk) {
                    acc[r][0] = fmaf(ar[kk], w4[kk].x, acc[r][0]);
                    acc[r][1] = fmaf(ar[kk], w4[kk].y, acc[r][1]);
                    acc[r][2] = fmaf(ar[kk], w4[kk].z, acc[r][2]);
                    acc[r][3] = fmaf(ar[kk], w4[kk].w, acc[r][3]);
                }
            }
        }
        if (c < 7) ((float4*)&Wb[buf ^ 1][0][0])[t] = wnext;
        __syncthreads();
    }

    const int c0 = tx * 4;
    const float4* W24 = (const float4*)W2;
    float4 w2pre = W24[t];
    {
        float b1v[4], sc[4], sh[4];
#pragma unroll
        for (int c = 0; c < 4; ++c) {
            b1v[c] = b1[c0 + c];
            float s = gam[c0 + c] * rsqrtf(var[c0 + c] + 1e-5f);
            sc[c] = s;
            sh[c] = bet[c0 + c] - mu[c0 + c] * s;
        }
#pragma unroll
        for (int r = 0; r < 4; ++r) {
            float4 y;
            y.x = fmaxf(fmaf(acc[r][0] + b1v[0], sc[0], sh[0]), 0.f);
            y.y = fmaxf(fmaf(acc[r][1] + b1v[1], sc[1], sh[1]), 0.f);
            y.z = fmaxf(fmaf(acc[r][2] + b1v[2], sc[2], sh[2]), 0.f);
            y.w = fmaxf(fmaf(acc[r][3] + b1v[3], sc[3], sh[3]), 0.f);
            *(float4*)&At[ty * 4 + r][c0] = y;
            acc[r][0] = 0.f; acc[r][1] = 0.f; acc[r][2] = 0.f; acc[r][3] = 0.f;
        }
    }
    ((float4*)&Wb[0][0][0])[t] = w2pre;
    __syncthreads();

    for (int c = 0; c < 8; ++c) {
        const int buf = c & 1;
        float4 wnext;
        if (c < 7) wnext = W24[(c + 1) * 512 + t];
#pragma unroll
        for (int g = 0; g < 4; ++g) {
            float4 w4[4];
#pragma unroll
            for (int kk = 0; kk < 4; ++kk) w4[kk] = *(const float4*)&Wb[buf][g * 4 + kk][tx * 4];
#pragma unroll
            for (int r = 0; r < 4; ++r) {
                float4 a = *(const float4*)&At[ty * 4 + r][c * 16 + g * 4];
                float ar[4] = {a.x, a.y, a.z, a.w};
#pragma unroll
                for (int kk = 0; kk < 4; ++kk) {
                    acc[r][0] = fmaf(ar[kk], w4[kk].x, acc[r][0]);
                    acc[r][1] = fmaf(ar[kk], w4[kk].y, acc[r][1]);
                    acc[r][2] = fmaf(ar[kk], w4[kk].z, acc[r][2]);
                    acc[r][3] = fmaf(ar[kk], w4[kk].w, acc[r][3]);
                }
            }
        }
        if (c < 7) ((float4*)&Wb[buf ^ 1][0][0])[t] = wnext;
        __syncthreads();
    }

    float b2v[4];
#pragma unroll
    for (int c = 0; c < 4; ++c) b2v[c] = b2[c0 + c];
#pragma unroll
    for (int r = 0; r < 4; ++r) {
        int row = row0 + ty * 4 + r;
        if (row < n) {
            float4 o;
            o.x = fmaxf(acc[r][0] + b2v[0], 0.f);
            o.y = fmaxf(acc[r][1] + b2v[1], 0.f);
            o.z = fmaxf(acc[r][2] + b2v[2], 0.f);
            o.w = fmaxf(acc[r][3] + b2v[3], 0.f);
            *(float4*)&H[(size_t)row * 128 + c0] = o;
        }
    }
}

// ---------------------------------------------------------------------------
// Last-resort fallback: scale_init + atomic edge kernel
// ---------------------------------------------------------------------------
__global__ void scale_init(const float* __restrict__ h, float* __restrict__ z,
                           const float* __restrict__ eps, int layer, int n4)
{
    const float s = 1.0f + eps[layer];
    int i = blockIdx.x * blockDim.x + threadIdx.x;
    const int stride = gridDim.x * blockDim.x;
    const float4* h4 = (const float4*)h;
    float4* z4 = (float4*)z;
    for (; i < n4; i += stride) {
        float4 v = h4[i];
        v.x *= s; v.y *= s; v.z *= s; v.w *= s;
        z4[i] = v;
    }
}

__global__ __launch_bounds__(256) void edge_atomic(
    const float* __restrict__ h, const int* __restrict__ ei,
    const float* __restrict__ eattr, const float* __restrict__ eatten,
    const float* __restrict__ W_ee, const float* __restrict__ b_ee,
    float* __restrict__ Z, int E)
{
    __shared__ float Wee[16][128];
    __shared__ float bee[128];
    const int t = threadIdx.x;
    const float4* We4 = (const float4*)W_ee;
    float4* Ws4 = (float4*)&Wee[0][0];
#pragma unroll
    for (int i = 0; i < 2; ++i) Ws4[t + 256 * i] = We4[t + 256 * i];
    if (t < 128) bee[t] = b_ee[t];
    __syncthreads();

    const int lane = t & 63;
    const int c = lane * 2;
    const long wid = (long)blockIdx.x * 4 + (t >> 6);
    const long nw = (long)gridDim.x * 4;
    for (long e = wid; e < E; e += nw) {
        const int src = ei[e];
        const int dst = ei[E + e];
        const float att = eatten[e];
        union { float4 v4[4]; float f[16]; } ea;
        const float4* eap = (const float4*)(eattr + e * 16);
        ea.v4[0] = eap[0]; ea.v4[1] = eap[1]; ea.v4[2] = eap[2]; ea.v4[3] = eap[3];
        float2 hv = *(const float2*)&h[(size_t)src * 128 + c];
        float e0 = bee[c], e1 = bee[c + 1];
#pragma unroll
        for (int k = 0; k < 16; ++k) {
            float2 w = *(const float2*)&Wee[k][c];
            e0 = fmaf(ea.f[k], w.x, e0);
            e1 = fmaf(ea.f[k], w.y, e1);
        }
        float m0 = fmaxf(hv.x + e0, 0.f) * att;
        float m1 = fmaxf(hv.y + e1, 0.f) * att;
        atomic_add2(&Z[(size_t)dst * 128 + c], m0, m1);
    }
}

extern "C" void kernel_launch(void* const* d_in, const int* in_sizes, int n_in,
                              void* d_out, int out_size, void* d_ws, size_t ws_size,
                              hipStream_t stream)
{
    const float* x      = (const float*)d_in[0];
    const int*   ei     = (const int*)d_in[1];
    // d_in[2] = batch (unused)
    const float* eattr  = (const float*)d_in[3];
    const float* eatten = (const float*)d_in[4];
    const float* W_enc  = (const float*)d_in[5];
    const float* b_enc  = (const float*)d_in[6];
    const float* W_ee   = (const float*)d_in[7];
    const float* b_ee   = (const float*)d_in[8];
    const float* eps    = (const float*)d_in[9];
    const float* W1     = (const float*)d_in[10];
    const float* b1     = (const float*)d_in[11];
    const float* gam    = (const float*)d_in[12];
    const float* bet    = (const float*)d_in[13];
    const float* mu     = (const float*)d_in[14];
    const float* var    = (const float*)d_in[15];
    const float* W2     = (const float*)d_in[16];
    const float* b2     = (const float*)d_in[17];

    const int N = in_sizes[0] / 128;
    const int E = in_sizes[1] / 2;
    const int L = in_sizes[9];

    float* h = (float*)d_out;   // [N,128]

    // workspace layout
    char* p = (char*)d_ws;
    float* zbuf = (float*)p;            p += ((size_t)N * 128 * 4 + 255) & ~(size_t)255;
    int* off  = (int*)p;                p += 4 * (size_t)(N + 1);
    int* cur  = (int*)p;                p += 4 * (size_t)N;
    int* cnt  = (int*)p;                p += 4 * (size_t)N;
    int* eids = (int*)p;                p += 4 * (size_t)E;
    const size_t need_csr = (size_t)(p - (char*)d_ws);
    int*   srcp = (int*)p;              p += 4 * (size_t)E;
    float* attp = (float*)p;            p += 4 * (size_t)E;
    const size_t need_perm = (size_t)(p - (char*)d_ws);
    p = (char*)(((uintptr_t)p + 255) & ~(uintptr_t)255);
    uint32_t* eab = (uint32_t*)p;
    const size_t need_eaf16 = (size_t)(p - (char*)d_ws) + 256 * (size_t)E;

    const bool use_csr  = ws_size >= need_csr;
    const bool use_perm = ws_size >= need_perm;
    const bool use_ea16 = ws_size >= need_eaf16;

    const int tiles = (N + 63) / 64;

    gemm_enc<<<tiles, 512, 0, stream>>>(x, W_enc, b_enc, h, N);

    if (use_csr) {
        zero_cnt<<<(N + 255) / 256, 256, 0, stream>>>(cnt, N);
        hist_kernel<<<1024, 256, 0, stream>>>(ei, cnt, E);
        scan_kernel<<<1, 1024, 0, stream>>>(cnt, off, cur, N, E);
        scatter_kernel<<<1024, 256, 0, stream>>>(ei, cur, eids, E);
        if (use_perm)
            permute_kernel<<<1024, 256, 0, stream>>>(ei, eatten, eids, srcp, attp, E);
        if (use_ea16)
            eabuild_staged<<<(E + 255) / 256, 256, 0, stream>>>(eids, eattr, W_ee, b_ee, eab, E);
    }

    for (int i = 0; i < L; ++i) {
        if (use_ea16) {
            agg_f16<<<(N + 3) / 4, 256, 0, stream>>>(
                h, srcp, attp, eab, off, zbuf, eps, i, N);
        } else if (use_perm) {
            agg_gather<false><<<(N + 3) / 4, 256, 0, stream>>>(
                h, srcp, attp, nullptr, eids, eattr, off, W_ee, b_ee, zbuf, eps, i, N);
        } else {
            scale_init<<<2048, 256, 0, stream>>>(h, zbuf, eps, i, N * 128 / 4);
            edge_atomic<<<2048, 256, 0, stream>>>(h, ei, eattr, eatten, W_ee, b_ee, zbuf, E);
        }
        gemm_mlp<<<tiles, 512, 0, stream>>>(
            zbuf, W1 + (size_t)i * 128 * 128, b1 + i * 128,
            gam + i * 128, bet + i * 128, mu + i * 128, var + i * 128,
            W2 + (size_t)i * 128 * 128, b2 + i * 128,
            h, N);
    }
}

// Round 7
// 897.416 us; speedup vs baseline: 1.2174x; 1.0187x over previous
//
#include <hip/hip_runtime.h>
#include <hip/hip_fp16.h>
#include <cstdint>
#include <cstddef>

// ---------------------------------------------------------------------------
// GIN (GINEConv x3) forward, f32.
//   h  = x@W_enc + b_enc                                  (gemm_enc -> w0)
//   CSR build: hist -> scan(3-pass) -> scatter -> permute -> eabuild(f16)
//   per layer i (fused): block aggregates its 64 nodes into LDS, then
//     h_out = relu( relu(BN(z@W1+b1)) @ W2 + b2 )  (ping-pong w0/w1 -> d_out)
// ---------------------------------------------------------------------------

// ---- packed-f32x2 atomic with compile-safe fallback (fallback path only) ---
template <class T>
__device__ inline auto add2_impl(T* p, T v, int)
    -> decltype(unsafeAtomicAdd(p, v), void()) {
    unsafeAtomicAdd(p, v);
}
template <class T>
__device__ inline void add2_impl(T* p, T v, long) {
    unsafeAtomicAdd(&p->x, v.x);
    unsafeAtomicAdd(&p->y, v.y);
}
__device__ inline void atomic_add2(float* p, float x, float y) {
    add2_impl(reinterpret_cast<float2*>(p), make_float2(x, y), 0);
}

// ---------------------------------------------------------------------------
// CSR build
// ---------------------------------------------------------------------------
__global__ void zero_cnt(int* __restrict__ cnt, int N)
{
    int i = blockIdx.x * blockDim.x + threadIdx.x;
    if (i < N) cnt[i] = 0;
}

__global__ void hist_kernel(const int* __restrict__ ei, int* __restrict__ cnt, int E)
{
    int i = blockIdx.x * blockDim.x + threadIdx.x;
    const int st = gridDim.x * blockDim.x;
    for (; i < E; i += st) atomicAdd(&cnt[ei[E + i]], 1);
}

// ---- 3-pass scan: 1024 elems/block, 256 threads x 4 elems ----
__global__ __launch_bounds__(256) void scan_pass1(
    const int* __restrict__ cnt, int* __restrict__ bsum, int N)
{
    __shared__ int part[256];
    const int t = threadIdx.x;
    const int base = blockIdx.x * 1024 + t * 4;
    int s = 0;
#pragma unroll
    for (int j = 0; j < 4; ++j) {
        int idx = base + j;
        if (idx < N) s += cnt[idx];
    }
    part[t] = s;
    __syncthreads();
    for (int d = 128; d > 0; d >>= 1) {
        if (t < d) part[t] += part[t + d];
        __syncthreads();
    }
    if (t == 0) bsum[blockIdx.x] = part[0];
}

__global__ __launch_bounds__(256) void scan_pass2(
    int* __restrict__ bsum, int* __restrict__ off, int NB, int N, int E)
{
    __shared__ int sb[1024];
    const int t = threadIdx.x;
    for (int i = t; i < NB; i += 256) sb[i] = bsum[i];
    __syncthreads();
    if (t == 0) {
        int run = 0;
        for (int i = 0; i < NB; ++i) { int v = sb[i]; sb[i] = run; run += v; }
        off[N] = E;
    }
    __syncthreads();
    for (int i = t; i < NB; i += 256) bsum[i] = sb[i];
}

__global__ __launch_bounds__(256) void scan_pass3(
    const int* __restrict__ cnt, const int* __restrict__ bsum,
    int* __restrict__ off, int* __restrict__ cur, int N)
{
    __shared__ int part[256];
    const int t = threadIdx.x;
    const int base = blockIdx.x * 1024 + t * 4;
    int v[4]; int s = 0;
#pragma unroll
    for (int j = 0; j < 4; ++j) {
        int idx = base + j;
        v[j] = (idx < N) ? cnt[idx] : 0;
        s += v[j];
    }
    part[t] = s;
    __syncthreads();
    for (int d = 1; d < 256; d <<= 1) {
        int x = (t >= d) ? part[t - d] : 0;
        __syncthreads();
        part[t] += x;
        __syncthreads();
    }
    int run = bsum[blockIdx.x] + part[t] - s;   // exclusive base for this thread
#pragma unroll
    for (int j = 0; j < 4; ++j) {
        int idx = base + j;
        if (idx < N) { off[idx] = run; cur[idx] = run; }
        run += v[j];
    }
}

__global__ void scatter_kernel(const int* __restrict__ ei, int* __restrict__ cur,
                               int* __restrict__ eids, int E)
{
    int i = blockIdx.x * blockDim.x + threadIdx.x;
    const int st = gridDim.x * blockDim.x;
    for (; i < E; i += st) {
        int pos = atomicAdd(&cur[ei[E + i]], 1);
        eids[pos] = i;
    }
}

__global__ void permute_kernel(
    const int* __restrict__ ei, const float* __restrict__ eatten,
    const int* __restrict__ eids,
    int* __restrict__ srcp, float* __restrict__ attp, int E)
{
    int i = blockIdx.x * blockDim.x + threadIdx.x;
    const int st = gridDim.x * blockDim.x;
    for (; i < E; i += st) {
        const int eid = eids[i];
        srcp[i] = ei[eid];
        attp[i] = eatten[eid];
    }
}

// ---------------------------------------------------------------------------
// eabuild (staged): ea = edge_attr@W_ee + b_ee in CSR slot order, packed half2.
// ---------------------------------------------------------------------------
__global__ __launch_bounds__(256) void eabuild_staged(
    const int* __restrict__ eids, const float* __restrict__ eattr,
    const float* __restrict__ W_ee, const float* __restrict__ b_ee,
    uint32_t* __restrict__ eab, int E)
{
    __shared__ int   se[256];
    __shared__ float sattr[256 * 16];
    const int t = threadIdx.x;
    const int lane = t & 63;
    const int wv = t >> 6;
    const int c = lane * 2;

    float2 w[16];
#pragma unroll
    for (int k = 0; k < 16; ++k) w[k] = *(const float2*)&W_ee[k * 128 + c];
    const float2 bv = *(const float2*)&b_ee[c];

    const int base = blockIdx.x * 256;
    const int n = min(256, E - base);
    if (n <= 0) return;

    if (t < n) se[t] = eids[base + t];
    __syncthreads();

    float4* sa4 = (float4*)sattr;
    const float4* ea4 = (const float4*)eattr;
    for (int i = t; i < n * 4; i += 256) {
        const int row = i >> 2, part = i & 3;
        sa4[i] = ea4[(size_t)se[row] * 4 + part];
    }
    __syncthreads();

    for (int slot = wv; slot < n; slot += 4) {
        const float4* sr = (const float4*)&sattr[slot * 16];
        float4 e0 = sr[0], e1 = sr[1], e2 = sr[2], e3 = sr[3];
        const float ef[16] = {e0.x, e0.y, e0.z, e0.w, e1.x, e1.y, e1.z, e1.w,
                              e2.x, e2.y, e2.z, e2.w, e3.x, e3.y, e3.z, e3.w};
        float d0 = bv.x, d1 = bv.y;
#pragma unroll
        for (int k = 0; k < 16; ++k) {
            d0 = fmaf(ef[k], w[k].x, d0);
            d1 = fmaf(ef[k], w[k].y, d1);
        }
        __half2 hh = __floats2half2_rn(d0, d1);
        eab[(size_t)(base + slot) * 64 + lane] = *reinterpret_cast<uint32_t*>(&hh);
    }
}

// ---------------------------------------------------------------------------
// FUSED layer: agg (64 nodes -> LDS) + MLP (GEMM1+BN+ReLU+GEMM2+ReLU).
// h_in/h_out must be distinct buffers.
// ---------------------------------------------------------------------------
__global__ __launch_bounds__(512, 4) void layer_fused(
    const float* __restrict__ h_in,
    const int* __restrict__ srcp, const float* __restrict__ attp,
    const uint32_t* __restrict__ eab, const int* __restrict__ off,
    const float* __restrict__ W1, const float* __restrict__ b1,
    const float* __restrict__ gam, const float* __restrict__ bet,
    const float* __restrict__ mu, const float* __restrict__ var,
    const float* __restrict__ W2, const float* __restrict__ b2,
    float* __restrict__ h_out, const float* __restrict__ eps, int layer, int n)
{
    __shared__ float At[64][128];     // z tile, then Y tile
    __shared__ float Wb[2][16][128];
    const int t = threadIdx.x;
    const int lane = t & 63;
    const int wv = t >> 6;            // 0..7
    const int c = lane * 2;
    const int row0 = blockIdx.x * 64;

    // stage W1 chunk 0 while agg runs
    const float4* W14 = (const float4*)W1;
    ((float4*)&Wb[0][0][0])[t] = W14[t];

    // ---- phase A: aggregation into At (each wave: 8 nodes) ----
    const float sc = 1.0f + eps[layer];
    for (int r = wv; r < 64; r += 8) {
        const int v = row0 + r;
        if (v >= n) { *(float2*)&At[r][c] = make_float2(0.f, 0.f); continue; }
        const int e0 = off[v], e1 = off[v + 1];
        float a0 = 0.f, a1 = 0.f;
        int e = e0;
        for (; e + 8 <= e1; e += 8) {
            int s[8]; float at[8]; uint32_t ea[8];
#pragma unroll
            for (int u = 0; u < 8; ++u) s[u] = srcp[e + u];
#pragma unroll
            for (int u = 0; u < 8; ++u) at[u] = attp[e + u];
#pragma unroll
            for (int u = 0; u < 8; ++u) ea[u] = eab[(size_t)(e + u) * 64 + lane];
            float2 hv[8];
#pragma unroll
            for (int u = 0; u < 8; ++u)
                hv[u] = *(const float2*)&h_in[(size_t)s[u] * 128 + c];
#pragma unroll
            for (int u = 0; u < 8; ++u) {
                const __half2 hh = *reinterpret_cast<const __half2*>(&ea[u]);
                a0 += fmaxf(hv[u].x + __half2float(__low2half(hh)), 0.f) * at[u];
                a1 += fmaxf(hv[u].y + __half2float(__high2half(hh)), 0.f) * at[u];
            }
        }
        for (; e < e1; ++e) {
            const int s = srcp[e];
            const float at = attp[e];
            const uint32_t ea = eab[(size_t)e * 64 + lane];
            const float2 hv = *(const float2*)&h_in[(size_t)s * 128 + c];
            const __half2 hh = *reinterpret_cast<const __half2*>(&ea);
            a0 += fmaxf(hv.x + __half2float(__low2half(hh)), 0.f) * at;
            a1 += fmaxf(hv.y + __half2float(__high2half(hh)), 0.f) * at;
        }
        const float2 hv = *(const float2*)&h_in[(size_t)v * 128 + c];
        At[r][c]     = fmaf(sc, hv.x, a0);
        At[r][c + 1] = fmaf(sc, hv.y, a1);
    }
    __syncthreads();

    // ---- phase B: GEMM1 ----
    const int tx = t & 31, ty = t >> 5;
    float acc[4][4] = {};
    for (int cc = 0; cc < 8; ++cc) {
        const int buf = cc & 1;
        float4 wnext;
        if (cc < 7) wnext = W14[(cc + 1) * 512 + t];
#pragma unroll
        for (int g = 0; g < 4; ++g) {
            float4 w4[4];
#pragma unroll
            for (int kk = 0; kk < 4; ++kk) w4[kk] = *(const float4*)&Wb[buf][g * 4 + kk][tx * 4];
#pragma unroll
            for (int r = 0; r < 4; ++r) {
                float4 a = *(const float4*)&At[ty * 4 + r][cc * 16 + g * 4];
                float ar[4] = {a.x, a.y, a.z, a.w};
#pragma unroll
                for (int kk = 0; kk < 4; ++kk) {
                    acc[r][0] = fmaf(ar[kk], w4[kk].x, acc[r][0]);
                    acc[r][1] = fmaf(ar[kk], w4[kk].y, acc[r][1]);
                    acc[r][2] = fmaf(ar[kk], w4[kk].z, acc[r][2]);
                    acc[r][3] = fmaf(ar[kk], w4[kk].w, acc[r][3]);
                }
            }
        }
        if (cc < 7) ((float4*)&Wb[buf ^ 1][0][0])[t] = wnext;
        __syncthreads();
    }

    // ---- BN + ReLU -> At, stage W2 chunk 0 ----
    const int c0 = tx * 4;
    const float4* W24 = (const float4*)W2;
    float4 w2pre = W24[t];
    {
        float b1v[4], scv[4], shv[4];
#pragma unroll
        for (int cl = 0; cl < 4; ++cl) {
            b1v[cl] = b1[c0 + cl];
            float s = gam[c0 + cl] * rsqrtf(var[c0 + cl] + 1e-5f);
            scv[cl] = s;
            shv[cl] = bet[c0 + cl] - mu[c0 + cl] * s;
        }
#pragma unroll
        for (int r = 0; r < 4; ++r) {
            float4 y;
            y.x = fmaxf(fmaf(acc[r][0] + b1v[0], scv[0], shv[0]), 0.f);
            y.y = fmaxf(fmaf(acc[r][1] + b1v[1], scv[1], shv[1]), 0.f);
            y.z = fmaxf(fmaf(acc[r][2] + b1v[2], scv[2], shv[2]), 0.f);
            y.w = fmaxf(fmaf(acc[r][3] + b1v[3], scv[3], shv[3]), 0.f);
            *(float4*)&At[ty * 4 + r][c0] = y;
            acc[r][0] = 0.f; acc[r][1] = 0.f; acc[r][2] = 0.f; acc[r][3] = 0.f;
        }
    }
    ((float4*)&Wb[0][0][0])[t] = w2pre;
    __syncthreads();

    // ---- GEMM2 ----
    for (int cc = 0; cc < 8; ++cc) {
        const int buf = cc & 1;
        float4 wnext;
        if (cc < 7) wnext = W24[(cc + 1) * 512 + t];
#pragma unroll
        for (int g = 0; g < 4; ++g) {
            float4 w4[4];
#pragma unroll
            for (int kk = 0; kk < 4; ++kk) w4[kk] = *(const float4*)&Wb[buf][g * 4 + kk][tx * 4];
#pragma unroll
            for (int r = 0; r < 4; ++r) {
                float4 a = *(const float4*)&At[ty * 4 + r][cc * 16 + g * 4];
                float ar[4] = {a.x, a.y, a.z, a.w};
#pragma unroll
                for (int kk = 0; kk < 4; ++kk) {
                    acc[r][0] = fmaf(ar[kk], w4[kk].x, acc[r][0]);
                    acc[r][1] = fmaf(ar[kk], w4[kk].y, acc[r][1]);
                    acc[r][2] = fmaf(ar[kk], w4[kk].z, acc[r][2]);
                    acc[r][3] = fmaf(ar[kk], w4[kk].w, acc[r][3]);
                }
            }
        }
        if (cc < 7) ((float4*)&Wb[buf ^ 1][0][0])[t] = wnext;
        __syncthreads();
    }

    float b2v[4];
#pragma unroll
    for (int cl = 0; cl < 4; ++cl) b2v[cl] = b2[c0 + cl];
#pragma unroll
    for (int r = 0; r < 4; ++r) {
        int row = row0 + ty * 4 + r;
        if (row < n) {
            float4 o;
            o.x = fmaxf(acc[r][0] + b2v[0], 0.f);
            o.y = fmaxf(acc[r][1] + b2v[1], 0.f);
            o.z = fmaxf(acc[r][2] + b2v[2], 0.f);
            o.w = fmaxf(acc[r][3] + b2v[3], 0.f);
            *(float4*)&h_out[(size_t)row * 128 + c0] = o;
        }
    }
}

// ---------------------------------------------------------------------------
// Encoder GEMM: h = A@W + b.
// ---------------------------------------------------------------------------
__global__ __launch_bounds__(512, 4) void gemm_enc(
    const float* __restrict__ A, const float* __restrict__ W,
    const float* __restrict__ bias, float* __restrict__ H, int n)
{
    __shared__ float At[64][128];
    __shared__ float Wb[2][16][128];
    const int t = threadIdx.x;
    const int tx = t & 31, ty = t >> 5;

    const int row0 = blockIdx.x * 64;
    const int nrows = min(64, n - row0);
    const int lim = nrows * 32;
    const float4* A4 = (const float4*)(A + (size_t)row0 * 128);
    float4* At4 = (float4*)&At[0][0];
#pragma unroll
    for (int i = 0; i < 4; ++i) {
        int idx = t + 512 * i;
        if (idx < lim) At4[idx] = A4[idx];
    }
    const float4* W4 = (const float4*)W;
    ((float4*)&Wb[0][0][0])[t] = W4[t];
    __syncthreads();

    float acc[4][4] = {};
    for (int c = 0; c < 8; ++c) {
        const int buf = c & 1;
        float4 wnext;
        if (c < 7) wnext = W4[(c + 1) * 512 + t];
#pragma unroll
        for (int g = 0; g < 4; ++g) {
            float4 w4[4];
#pragma unroll
            for (int kk = 0; kk < 4; ++kk) w4[kk] = *(const float4*)&Wb[buf][g * 4 + kk][tx * 4];
#pragma unroll
            for (int r = 0; r < 4; ++r) {
                float4 a = *(const float4*)&At[ty * 4 + r][c * 16 + g * 4];
                float ar[4] = {a.x, a.y, a.z, a.w};
#pragma unroll
                for (int kk = 0; kk < 4; ++kk) {
                    acc[r][0] = fmaf(ar[kk], w4[kk].x, acc[r][0]);
                    acc[r][1] = fmaf(ar[kk], w4[kk].y, acc[r][1]);
                    acc[r][2] = fmaf(ar[kk], w4[kk].z, acc[r][2]);
                    acc[r][3] = fmaf(ar[kk], w4[kk].w, acc[r][3]);
                }
            }
        }
        if (c < 7) ((float4*)&Wb[buf ^ 1][0][0])[t] = wnext;
        __syncthreads();
    }

    const int c0 = tx * 4;
    float bvv[4];
#pragma unroll
    for (int c = 0; c < 4; ++c) bvv[c] = bias[c0 + c];
#pragma unroll
    for (int r = 0; r < 4; ++r) {
        int row = row0 + ty * 4 + r;
        if (row < n) {
            float4 o;
            o.x = acc[r][0] + bvv[0]; o.y = acc[r][1] + bvv[1];
            o.z = acc[r][2] + bvv[2]; o.w = acc[r][3] + bvv[3];
            *(float4*)&H[(size_t)row * 128 + c0] = o;
        }
    }
}

// ---------------------------------------------------------------------------
// Fallback: separate agg (f16 tier) + gemm_mlp, and atomic tier.
// ---------------------------------------------------------------------------
__global__ __launch_bounds__(256) void agg_f16(
    const float* __restrict__ h, const int* __restrict__ srcp,
    const float* __restrict__ attp, const uint32_t* __restrict__ eab,
    const int* __restrict__ off,
    float* __restrict__ Z, const float* __restrict__ eps, int layer, int N)
{
    const int t = threadIdx.x;
    const int v = blockIdx.x * 4 + (t >> 6);
    if (v >= N) return;
    const int lane = t & 63;
    const int c = lane * 2;

    const int e0 = off[v], e1 = off[v + 1];
    float a0 = 0.f, a1 = 0.f;
    int e = e0;
    for (; e + 8 <= e1; e += 8) {
        int s[8]; float at[8]; uint32_t ea[8];
#pragma unroll
        for (int u = 0; u < 8; ++u) s[u] = srcp[e + u];
#pragma unroll
        for (int u = 0; u < 8; ++u) at[u] = attp[e + u];
#pragma unroll
        for (int u = 0; u < 8; ++u) ea[u] = eab[(size_t)(e + u) * 64 + lane];
        float2 hv[8];
#pragma unroll
        for (int u = 0; u < 8; ++u)
            hv[u] = *(const float2*)&h[(size_t)s[u] * 128 + c];
#pragma unroll
        for (int u = 0; u < 8; ++u) {
            const __half2 hh = *reinterpret_cast<const __half2*>(&ea[u]);
            a0 += fmaxf(hv[u].x + __half2float(__low2half(hh)), 0.f) * at[u];
            a1 += fmaxf(hv[u].y + __half2float(__high2half(hh)), 0.f) * at[u];
        }
    }
    for (; e < e1; ++e) {
        const int s = srcp[e];
        const float at = attp[e];
        const uint32_t ea = eab[(size_t)e * 64 + lane];
        const float2 hv = *(const float2*)&h[(size_t)s * 128 + c];
        const __half2 hh = *reinterpret_cast<const __half2*>(&ea);
        a0 += fmaxf(hv.x + __half2float(__low2half(hh)), 0.f) * at;
        a1 += fmaxf(hv.y + __half2float(__high2half(hh)), 0.f) * at;
    }

    const float sc = 1.0f + eps[layer];
    const float2 hv = *(const float2*)&h[(size_t)v * 128 + c];
    float2 z;
    z.x = fmaf(sc, hv.x, a0);
    z.y = fmaf(sc, hv.y, a1);
    *(float2*)&Z[(size_t)v * 128 + c] = z;
}

__global__ __launch_bounds__(512, 4) void gemm_mlp(
    const float* __restrict__ Z,
    const float* __restrict__ W1, const float* __restrict__ b1,
    const float* __restrict__ gam, const float* __restrict__ bet,
    const float* __restrict__ mu, const float* __restrict__ var,
    const float* __restrict__ W2, const float* __restrict__ b2,
    float* __restrict__ H, int n)
{
    __shared__ float At[64][128];
    __shared__ float Wb[2][16][128];
    const int t = threadIdx.x;
    const int tx = t & 31, ty = t >> 5;

    const int row0 = blockIdx.x * 64;
    const int nrows = min(64, n - row0);
    const int lim = nrows * 32;
    const float4* Z4 = (const float4*)(Z + (size_t)row0 * 128);
    float4* At4 = (float4*)&At[0][0];
#pragma unroll
    for (int i = 0; i < 4; ++i) {
        int idx = t + 512 * i;
        if (idx < lim) At4[idx] = Z4[idx];
    }
    const float4* W14 = (const float4*)W1;
    ((float4*)&Wb[0][0][0])[t] = W14[t];
    __syncthreads();

    float acc[4][4] = {};
    for (int c = 0; c < 8; ++c) {
        const int buf = c & 1;
        float4 wnext;
        if (c < 7) wnext = W14[(c + 1) * 512 + t];
#pragma unroll
        for (int g = 0; g < 4; ++g) {
            float4 w4[4];
#pragma unroll
            for (int kk = 0; kk < 4; ++kk) w4[kk] = *(const float4*)&Wb[buf][g * 4 + kk][tx * 4];
#pragma unroll
            for (int r = 0; r < 4; ++r) {
                float4 a = *(const float4*)&At[ty * 4 + r][c * 16 + g * 4];
                float ar[4] = {a.x, a.y, a.z, a.w};
#pragma unroll
                for (int kk = 0; kk < 4; ++kk) {
                    acc[r][0] = fmaf(ar[kk], w4[kk].x, acc[r][0]);
                    acc[r][1] = fmaf(ar[kk], w4[kk].y, acc[r][1]);
                    acc[r][2] = fmaf(ar[kk], w4[kk].z, acc[r][2]);
                    acc[r][3] = fmaf(ar[kk], w4[kk].w, acc[r][3]);
                }
            }
        }
        if (c < 7) ((float4*)&Wb[buf ^ 1][0][0])[t] = wnext;
        __syncthreads();
    }

    const int c0 = tx * 4;
    const float4* W24 = (const float4*)W2;
    float4 w2pre = W24[t];
    {
        float b1v[4], scv[4], shv[4];
#pragma unroll
        for (int cl = 0; cl < 4; ++cl) {
            b1v[cl] = b1[c0 + cl];
            float s = gam[c0 + cl] * rsqrtf(var[c0 + cl] + 1e-5f);
            scv[cl] = s;
            shv[cl] = bet[c0 + cl] - mu[c0 + cl] * s;
        }
#pragma unroll
        for (int r = 0; r < 4; ++r) {
            float4 y;
            y.x = fmaxf(fmaf(acc[r][0] + b1v[0], scv[0], shv[0]), 0.f);
            y.y = fmaxf(fmaf(acc[r][1] + b1v[1], scv[1], shv[1]), 0.f);
            y.z = fmaxf(fmaf(acc[r][2] + b1v[2], scv[2], shv[2]), 0.f);
            y.w = fmaxf(fmaf(acc[r][3] + b1v[3], scv[3], shv[3]), 0.f);
            *(float4*)&At[ty * 4 + r][c0] = y;
            acc[r][0] = 0.f; acc[r][1] = 0.f; acc[r][2] = 0.f; acc[r][3] = 0.f;
        }
    }
    ((float4*)&Wb[0][0][0])[t] = w2pre;
    __syncthreads();

    for (int c = 0; c < 8; ++c) {
        const int buf = c & 1;
        float4 wnext;
        if (c < 7) wnext = W24[(c + 1) * 512 + t];
#pragma unroll
        for (int g = 0; g < 4; ++g) {
            float4 w4[4];
#pragma unroll
            for (int kk = 0; kk < 4; ++kk) w4[kk] = *(const float4*)&Wb[buf][g * 4 + kk][tx * 4];
#pragma unroll
            for (int r = 0; r < 4; ++r) {
                float4 a = *(const float4*)&At[ty * 4 + r][c * 16 + g * 4];
                float ar[4] = {a.x, a.y, a.z, a.w};
#pragma unroll
                for (int kk = 0; kk < 4; ++kk) {
                    acc[r][0] = fmaf(ar[kk], w4[kk].x, acc[r][0]);
                    acc[r][1] = fmaf(ar[kk], w4[kk].y, acc[r][1]);
                    acc[r][2] = fmaf(ar[kk], w4[kk].z, acc[r][2]);
                    acc[r][3] = fmaf(ar[kk], w4[kk].w, acc[r][3]);
                }
            }
        }
        if (c < 7) ((float4*)&Wb[buf ^ 1][0][0])[t] = wnext;
        __syncthreads();
    }

    float b2v[4];
#pragma unroll
    for (int cl = 0; cl < 4; ++cl) b2v[cl] = b2[c0 + cl];
#pragma unroll
    for (int r = 0; r < 4; ++r) {
        int row = row0 + ty * 4 + r;
        if (row < n) {
            float4 o;
            o.x = fmaxf(acc[r][0] + b2v[0], 0.f);
            o.y = fmaxf(acc[r][1] + b2v[1], 0.f);
            o.z = fmaxf(acc[r][2] + b2v[2], 0.f);
            o.w = fmaxf(acc[r][3] + b2v[3], 0.f);
            *(float4*)&H[(size_t)row * 128 + c0] = o;
        }
    }
}

__global__ void scale_init(const float* __restrict__ h, float* __restrict__ z,
                           const float* __restrict__ eps, int layer, int n4)
{
    const float s = 1.0f + eps[layer];
    int i = blockIdx.x * blockDim.x + threadIdx.x;
    const int stride = gridDim.x * blockDim.x;
    const float4* h4 = (const float4*)h;
    float4* z4 = (float4*)z;
    for (; i < n4; i += stride) {
        float4 v = h4[i];
        v.x *= s; v.y *= s; v.z *= s; v.w *= s;
        z4[i] = v;
    }
}

__global__ __launch_bounds__(256) void edge_atomic(
    const float* __restrict__ h, const int* __restrict__ ei,
    const float* __restrict__ eattr, const float* __restrict__ eatten,
    const float* __restrict__ W_ee, const float* __restrict__ b_ee,
    float* __restrict__ Z, int E)
{
    __shared__ float Wee[16][128];
    __shared__ float bee[128];
    const int t = threadIdx.x;
    const float4* We4 = (const float4*)W_ee;
    float4* Ws4 = (float4*)&Wee[0][0];
#pragma unroll
    for (int i = 0; i < 2; ++i) Ws4[t + 256 * i] = We4[t + 256 * i];
    if (t < 128) bee[t] = b_ee[t];
    __syncthreads();

    const int lane = t & 63;
    const int c = lane * 2;
    const long wid = (long)blockIdx.x * 4 + (t >> 6);
    const long nw = (long)gridDim.x * 4;
    for (long e = wid; e < E; e += nw) {
        const int src = ei[e];
        const int dst = ei[E + e];
        const float att = eatten[e];
        union { float4 v4[4]; float f[16]; } ea;
        const float4* eap = (const float4*)(eattr + e * 16);
        ea.v4[0] = eap[0]; ea.v4[1] = eap[1]; ea.v4[2] = eap[2]; ea.v4[3] = eap[3];
        float2 hv = *(const float2*)&h[(size_t)src * 128 + c];
        float e0 = bee[c], e1 = bee[c + 1];
#pragma unroll
        for (int k = 0; k < 16; ++k) {
            float2 w = *(const float2*)&Wee[k][c];
            e0 = fmaf(ea.f[k], w.x, e0);
            e1 = fmaf(ea.f[k], w.y, e1);
        }
        float m0 = fmaxf(hv.x + e0, 0.f) * att;
        float m1 = fmaxf(hv.y + e1, 0.f) * att;
        atomic_add2(&Z[(size_t)dst * 128 + c], m0, m1);
    }
}

extern "C" void kernel_launch(void* const* d_in, const int* in_sizes, int n_in,
                              void* d_out, int out_size, void* d_ws, size_t ws_size,
                              hipStream_t stream)
{
    const float* x      = (const float*)d_in[0];
    const int*   ei     = (const int*)d_in[1];
    // d_in[2] = batch (unused)
    const float* eattr  = (const float*)d_in[3];
    const float* eatten = (const float*)d_in[4];
    const float* W_enc  = (const float*)d_in[5];
    const float* b_enc  = (const float*)d_in[6];
    const float* W_ee   = (const float*)d_in[7];
    const float* b_ee   = (const float*)d_in[8];
    const float* eps    = (const float*)d_in[9];
    const float* W1     = (const float*)d_in[10];
    const float* b1     = (const float*)d_in[11];
    const float* gam    = (const float*)d_in[12];
    const float* bet    = (const float*)d_in[13];
    const float* mu     = (const float*)d_in[14];
    const float* var    = (const float*)d_in[15];
    const float* W2     = (const float*)d_in[16];
    const float* b2     = (const float*)d_in[17];

    const int N = in_sizes[0] / 128;
    const int E = in_sizes[1] / 2;
    const int L = in_sizes[9];

    float* hout = (float*)d_out;   // [N,128]

    // workspace layout
    const size_t hbytes = ((size_t)N * 128 * 4 + 255) & ~(size_t)255;
    char* p = (char*)d_ws;
    float* w0 = (float*)p;              p += hbytes;
    int* off  = (int*)p;                p += 4 * (size_t)(N + 1);
    int* cur  = (int*)p;                p += 4 * (size_t)N;
    int* cnt  = (int*)p;                p += 4 * (size_t)N;
    int* bsum = (int*)p;                p += 4 * 1024;
    int* eids = (int*)p;                p += 4 * (size_t)E;
    int*   srcp = (int*)p;              p += 4 * (size_t)E;
    float* attp = (float*)p;            p += 4 * (size_t)E;
    const size_t need_perm = (size_t)(p - (char*)d_ws);
    p = (char*)(((uintptr_t)p + 255) & ~(uintptr_t)255);
    uint32_t* eab = (uint32_t*)p;       p += 256 * (size_t)E;
    const size_t need_ea16 = (size_t)(p - (char*)d_ws);
    float* w1 = (float*)p;              p += hbytes;
    const size_t need_fused = (size_t)(p - (char*)d_ws);

    const bool use_perm  = ws_size >= need_perm;
    const bool use_ea16  = ws_size >= need_ea16;
    const bool use_fused = ws_size >= need_fused && (L % 2 == 1);

    const int tiles = (N + 63) / 64;
    const int NB = (N + 1023) / 1024;   // scan blocks (must be <= 1024)

    if (use_perm) {
        zero_cnt<<<(N + 255) / 256, 256, 0, stream>>>(cnt, N);
        hist_kernel<<<1024, 256, 0, stream>>>(ei, cnt, E);
        scan_pass1<<<NB, 256, 0, stream>>>(cnt, bsum, N);
        scan_pass2<<<1, 256, 0, stream>>>(bsum, off, NB, N, E);
        scan_pass3<<<NB, 256, 0, stream>>>(cnt, bsum, off, cur, N);
        scatter_kernel<<<1024, 256, 0, stream>>>(ei, cur, eids, E);
        permute_kernel<<<1024, 256, 0, stream>>>(ei, eatten, eids, srcp, attp, E);
        if (use_ea16)
            eabuild_staged<<<(E + 255) / 256, 256, 0, stream>>>(eids, eattr, W_ee, b_ee, eab, E);
    }

    if (use_fused && use_ea16) {
        // ping-pong: enc->w0; L0: w0->w1; L1: w1->w0; ...; last: ->d_out
        gemm_enc<<<tiles, 512, 0, stream>>>(x, W_enc, b_enc, w0, N);
        float* bufs[2] = {w0, w1};
        for (int i = 0; i < L; ++i) {
            const float* hin = bufs[i & 1];
            float* ho = (i == L - 1) ? hout : bufs[(i + 1) & 1];
            layer_fused<<<tiles, 512, 0, stream>>>(
                hin, srcp, attp, eab, off,
                W1 + (size_t)i * 128 * 128, b1 + i * 128,
                gam + i * 128, bet + i * 128, mu + i * 128, var + i * 128,
                W2 + (size_t)i * 128 * 128, b2 + i * 128,
                ho, eps, i, N);
        }
        return;
    }

    // fallback: h in d_out, zbuf = w0
    float* h = hout;
    float* zbuf = w0;
    gemm_enc<<<tiles, 512, 0, stream>>>(x, W_enc, b_enc, h, N);
    for (int i = 0; i < L; ++i) {
        if (use_ea16) {
            agg_f16<<<(N + 3) / 4, 256, 0, stream>>>(
                h, srcp, attp, eab, off, zbuf, eps, i, N);
        } else {
            scale_init<<<2048, 256, 0, stream>>>(h, zbuf, eps, i, N * 128 / 4);
            edge_atomic<<<2048, 256, 0, stream>>>(h, ei, eattr, eatten, W_ee, b_ee, zbuf, E);
        }
        gemm_mlp<<<tiles, 512, 0, stream>>>(
            zbuf, W1 + (size_t)i * 128 * 128, b1 + i * 128,
            gam + i * 128, bet + i * 128, mu + i * 128, var + i * 128,
            W2 + (size_t)i * 128 * 128, b2 + i * 128,
            h, N);
    }
}